// Round 17
// baseline (900.037 us; speedup 1.0000x reference)
//
#include <hip/hip_runtime.h>
#include <cstdint>
#include <cstddef>

#define DIMX 256
#define DIMV 512
#define DIMH 768
#define EPSV 0.05f

typedef __bf16 bf16x8 __attribute__((ext_vector_type(8)));
typedef unsigned short u16x8 __attribute__((ext_vector_type(8)));
typedef unsigned int u32x4 __attribute__((ext_vector_type(4)));
typedef float f32x4 __attribute__((ext_vector_type(4)));

__device__ __forceinline__ unsigned short f2bf(float f) {
  unsigned int u = __float_as_uint(f);
  u += 0x7fffu + ((u >> 16) & 1u);
  return (unsigned short)(u >> 16);
}
__device__ __forceinline__ float bf2f(unsigned short b) {
  return __uint_as_float(((unsigned int)b) << 16);
}
__device__ __forceinline__ bf16x8 ld8(const unsigned short* p) {
  u16x8 u = *reinterpret_cast<const u16x8*>(p);
  return __builtin_bit_cast(bf16x8, u);
}
__device__ __forceinline__ f32x4 mfma16(bf16x8 a, bf16x8 b, f32x4 c) {
  return __builtin_amdgcn_mfma_f32_16x16x32_bf16(a, b, c, 0, 0, 0);
}
__device__ __forceinline__ float rdlane(float v, int lane) {
  return __uint_as_float(
      (unsigned int)__builtin_amdgcn_readlane((int)__float_as_uint(v), lane));
}

// ============ K1: syrkP (blocks 0..255)  UNION  split (blocks 256..2559) ============
__global__ __launch_bounds__(256) void k_setup1(const float* __restrict__ X,
                                                unsigned short* __restrict__ Xhi,
                                                unsigned short* __restrict__ Xlo,
                                                const float* __restrict__ Pst,
                                                float* __restrict__ P) {
  int blk = blockIdx.x;
  if (blk < 256) {
    int bi = blk >> 4, bj = blk & 15;
    int ty = threadIdx.x >> 4, tx = threadIdx.x & 15;
    int i = bi * 16 + ty, j = bj * 16 + tx;
    const f32x4* ra = reinterpret_cast<const f32x4*>(Pst + (size_t)i * DIMX);
    const f32x4* rb = reinterpret_cast<const f32x4*>(Pst + (size_t)j * DIMX);
    float s = 0.f;
    for (int k = 0; k < 64; ++k) {
      f32x4 a = ra[k], b = rb[k];
      s = fmaf(a[0], b[0], s); s = fmaf(a[1], b[1], s);
      s = fmaf(a[2], b[2], s); s = fmaf(a[3], b[3], s);
    }
    P[(size_t)i * DIMX + j] = 0.5f * s + (i == j ? EPSV : 0.f);
  } else {
    int idx = (blk - 256) * 256 + threadIdx.x;
    if (idx < DIMH * DIMH) {
      float f = X[idx];
      unsigned short h = f2bf(f);
      Xhi[idx] = h;
      Xlo[idx] = f2bf(f - bf2f(h));
    }
  }
}

// ============ K2: chol+Linv (block 0, 16 WAVES)  UNION  syrkH (blocks 1..144) =======
// Round-16 chol ran 4 waves -> throughput phases latency-exposed (~160-200us wall).
// v17: 1024 threads. 64-VGPR cap (rounds 3/5/7) respected by PHASE-SPLITTING the
// serial state: pass A holds only d[32] (-> Ld to LDS, freed), pass B only wcol[32]
// (Ld via LDS broadcast). TRSM/SYRK/copy/Linv stride 1024 (4x waves). Linv reads the
// L panel from L2 directly (Lp2 staging dropped; LDS = Ld+Wl+T = 38KB).
__global__ __launch_bounds__(1024, 1) void k_setup2(float* __restrict__ A,
                                                    float* __restrict__ Li,
                                                    const unsigned short* __restrict__ Xhi,
                                                    const unsigned short* __restrict__ Xlo,
                                                    float* __restrict__ H) {
  __shared__ float Ld[32][33];
  __shared__ float Wl[32][33];
  __shared__ float T[32][232];
  int t = threadIdx.x;
  if (blockIdx.x == 0) {
    int wv = t >> 6, l = t & 63;
#pragma unroll 1
    for (int s = 0; s < 8; ++s) {
      int K = 32 * s;
      int R32 = 256 - K - 32;
      if (wv == 0) {
        int li = l & 31;
        // pass A: Cholesky of diag block, lane=row, d[32] only (~45 live regs)
        {
          float d[32];
#pragma unroll
          for (int j = 0; j < 32; ++j) d[j] = A[(K + j) * 256 + K + li];
#pragma unroll
          for (int k = 0; k < 32; ++k) {
            float dkk = rdlane(d[k], k);
            float ip = rsqrtf(dkk);
            d[k] *= ip;
#pragma unroll
            for (int j = k + 1; j < 32; ++j) {
              float ljk = rdlane(d[k], j);
              d[j] = fmaf(-ljk, d[k], d[j]);
            }
          }
          if (l < 32) {
#pragma unroll
            for (int j = 0; j < 32; ++j) Ld[li][j] = d[j];
          }
        }
        // pass B: W = Ld^{-1}, lane=column, wcol[32] only; Ld via same-wave LDS
        {
          float wcol[32];
#pragma unroll
          for (int i = 0; i < 32; ++i) {
            float Lii = Ld[i][i];
            float ipi = 1.0f / Lii;
            float acc = (li == i) ? 1.0f : 0.0f;
#pragma unroll
            for (int k = 0; k < i; ++k) {
              float Lik = Ld[i][k];
              acc = fmaf(-Lik, wcol[k], acc);
            }
            wcol[i] = acc * ipi;
          }
          if (l < 32) {
#pragma unroll
            for (int k = 0; k < 32; ++k) {
              Wl[k][l] = wcol[k];
              Li[(32 * s + k) * 256 + 32 * s + l] = wcol[k];  // Linv diag = W_s
            }
          }
        }
      }
      __syncthreads();
      if (R32 > 0) {
        // TRSM: L21 = A21 * W^T -> LDS T (16 waves)
        int nrt = R32 >> 2;
        for (int u = t; u < nrt * 8; u += 1024) {
          int rt = u >> 3, jg = u & 7;
          int r = K + 32 + rt * 4;
          int j0 = jg * 4;
          f32x4 z4 = {0.f, 0.f, 0.f, 0.f};
          f32x4 acc[4] = {z4, z4, z4, z4};
#pragma unroll
          for (int k = 0; k < 32; ++k) {
            f32x4 av = *reinterpret_cast<const f32x4*>(&A[(K + k) * 256 + r]);
#pragma unroll
            for (int jj = 0; jj < 4; ++jj) {
              float w = Wl[j0 + jj][k];
              acc[jj][0] = fmaf(av[0], w, acc[jj][0]);
              acc[jj][1] = fmaf(av[1], w, acc[jj][1]);
              acc[jj][2] = fmaf(av[2], w, acc[jj][2]);
              acc[jj][3] = fmaf(av[3], w, acc[jj][3]);
            }
          }
#pragma unroll
          for (int jj = 0; jj < 4; ++jj)
            *reinterpret_cast<f32x4*>(&T[j0 + jj][rt * 4]) = acc[jj];
        }
        __syncthreads();
        // copy T -> global A21 (one pass: 1024*4 >= 224)
        {
          int rl = t << 2;
          if (rl < R32) {
#pragma unroll 1
            for (int j = 0; j < 32; ++j)
              *reinterpret_cast<f32x4*>(&A[(K + j) * 256 + K + 32 + rl]) =
                  *reinterpret_cast<const f32x4*>(&T[j][rl]);
          }
        }
        // SYRK: A22 -= L21 L21^T (16 waves)
        int T4 = R32 >> 2;
        int ntile = T4 * (T4 + 1) / 2;
        for (int idx = t; idx < ntile; idx += 1024) {
          int ti = (int)((sqrtf(8.0f * (float)idx + 1.0f) - 1.0f) * 0.5f);
          while ((ti + 1) * (ti + 2) / 2 <= idx) ++ti;
          while (ti * (ti + 1) / 2 > idx) --ti;
          int tj = idx - ti * (ti + 1) / 2;
          int gi = K + 32 + 4 * ti, gj = K + 32 + 4 * tj;
          f32x4 acc[4];
#pragma unroll
          for (int jj = 0; jj < 4; ++jj)
            acc[jj] = *reinterpret_cast<const f32x4*>(&A[(gj + jj) * 256 + gi]);
#pragma unroll
          for (int k = 0; k < 32; ++k) {
            f32x4 av = *reinterpret_cast<const f32x4*>(&T[k][4 * ti]);
            f32x4 bv = *reinterpret_cast<const f32x4*>(&T[k][4 * tj]);
#pragma unroll
            for (int jj = 0; jj < 4; ++jj) {
              acc[jj][0] = fmaf(-av[0], bv[jj], acc[jj][0]);
              acc[jj][1] = fmaf(-av[1], bv[jj], acc[jj][1]);
              acc[jj][2] = fmaf(-av[2], bv[jj], acc[jj][2]);
              acc[jj][3] = fmaf(-av[3], bv[jj], acc[jj][3]);
            }
          }
#pragma unroll
          for (int jj = 0; jj < 4; ++jj)
            *reinterpret_cast<f32x4*>(&A[(gj + jj) * 256 + gi]) = acc[jj];
        }
      }
      __syncthreads();
    }

    // ---- Linv: for i=1..7, Linv_ij = -W_i * (sum_{k=j}^{i-1} L_ik Linv_kj) ----
    float* Tb = &T[0][0];
#pragma unroll 1
    for (int i = 1; i < 8; ++i) {
      if (t < 1024) {
        int r = t >> 5, kk = t & 31;
        Wl[r][kk] = Li[(32 * i + r) * 256 + 32 * i + kk];
      }
      __syncthreads();
      int nt1 = i * 64;
      // phase 1: T_j = sum_k L_ik Linv_kj  (L panel read direct from L2)
      for (int u = t; u < nt1; u += 1024) {
        int j = u >> 6, v = u & 63;
        int r0 = (v >> 3) * 4, c0 = (v & 7) * 4;
        f32x4 z4 = {0.f, 0.f, 0.f, 0.f};
        f32x4 acc[4] = {z4, z4, z4, z4};
        for (int k = j; k < i; ++k) {
#pragma unroll
          for (int kk = 0; kk < 32; ++kk) {
            f32x4 lp = *reinterpret_cast<const f32x4*>(
                &A[(32 * k + kk) * 256 + 32 * i + r0]);
            f32x4 lv = *reinterpret_cast<const f32x4*>(
                &Li[(32 * k + kk) * 256 + 32 * j + c0]);
#pragma unroll
            for (int e = 0; e < 4; ++e) {
              acc[e][0] = fmaf(lp[e], lv[0], acc[e][0]);
              acc[e][1] = fmaf(lp[e], lv[1], acc[e][1]);
              acc[e][2] = fmaf(lp[e], lv[2], acc[e][2]);
              acc[e][3] = fmaf(lp[e], lv[3], acc[e][3]);
            }
          }
        }
#pragma unroll
        for (int e = 0; e < 4; ++e)
          *reinterpret_cast<f32x4*>(&Tb[j * 1024 + (r0 + e) * 32 + c0]) = acc[e];
      }
      __syncthreads();
      // phase 2: Linv_ij = -W_i T_j
      for (int u = t; u < nt1; u += 1024) {
        int j = u >> 6, v = u & 63;
        int r0 = (v >> 3) * 4, c0 = (v & 7) * 4;
        f32x4 z4 = {0.f, 0.f, 0.f, 0.f};
        f32x4 acc[4] = {z4, z4, z4, z4};
#pragma unroll
        for (int kk = 0; kk < 32; ++kk) {
          f32x4 tv = *reinterpret_cast<const f32x4*>(&Tb[j * 1024 + kk * 32 + c0]);
#pragma unroll
          for (int e = 0; e < 4; ++e) {
            float w = Wl[r0 + e][kk];
            acc[e][0] = fmaf(-w, tv[0], acc[e][0]);
            acc[e][1] = fmaf(-w, tv[1], acc[e][1]);
            acc[e][2] = fmaf(-w, tv[2], acc[e][2]);
            acc[e][3] = fmaf(-w, tv[3], acc[e][3]);
          }
        }
#pragma unroll
        for (int e = 0; e < 4; ++e)
          *reinterpret_cast<f32x4*>(&Li[(32 * i + r0 + e) * 256 + 32 * j + c0]) =
              acc[e];
      }
      __syncthreads();
    }
  } else {
    // ---- syrkH on threads 0..255 (waves 4..15 exit; no barriers here) ----
    if (t >= 256) return;
    int b2 = blockIdx.x - 1;
    int bx = b2 % 12, by = b2 / 12;
    int i0 = by * 64, j0 = bx * 64;
    int l = t & 63, wv = t >> 6;
    int lr = l & 15, lq = l >> 4;
    int koff = lq * 8;
    int arow = i0 + wv * 16 + lr;
    f32x4 z = {0.f, 0.f, 0.f, 0.f};
    f32x4 acc[4] = {z, z, z, z};
    for (int pass = 0; pass < 3; ++pass) {
      const unsigned short* Xa = (pass == 2) ? Xlo : Xhi;
      const unsigned short* Xb = (pass == 1) ? Xlo : Xhi;
      for (int kc = 0; kc < 24; ++kc) {
        bf16x8 a = ld8(&Xa[(size_t)arow * DIMH + kc * 32 + koff]);
#pragma unroll
        for (int ct = 0; ct < 4; ++ct) {
          bf16x8 b = ld8(&Xb[(size_t)(j0 + ct * 16 + lr) * DIMH + kc * 32 + koff]);
          acc[ct] = mfma16(a, b, acc[ct]);
        }
      }
    }
#pragma unroll
    for (int ct = 0; ct < 4; ++ct)
#pragma unroll
      for (int r = 0; r < 4; ++r) {
        int i = i0 + wv * 16 + lq * 4 + r;
        int j = j0 + ct * 16 + lr;
        H[(size_t)i * DIMH + j] = acc[ct][r] + (i == j ? EPSV : 0.f);
      }
  }
}

// ============ K3: pinv (blocks 0..35)  UNION  gin (blocks 36..1571) =================
__global__ __launch_bounds__(256, 2) void k_setup3(const float* __restrict__ H,
                                                   const float* __restrict__ Chi,
                                                   unsigned short* __restrict__ Gin,
                                                   const float* __restrict__ Li,
                                                   float* __restrict__ Pinv) {
  int blk = blockIdx.x;
  int t = threadIdx.x;
  if (blk < 36) {
    int bi = (int)((sqrtf(8.0f * (float)blk + 1.0f) - 1.0f) * 0.5f);
    while ((bi + 1) * (bi + 2) / 2 <= blk) ++bi;
    while (bi * (bi + 1) / 2 > blk) --bi;
    int bj = blk - bi * (bi + 1) / 2;
    int r = t >> 3, c0 = (t & 7) * 4;
    f32x4 acc = {0.f, 0.f, 0.f, 0.f};
    for (int kb = bi; kb < 8; ++kb) {
#pragma unroll
      for (int kk = 0; kk < 32; ++kk) {
        float a = Li[(32 * kb + kk) * 256 + 32 * bi + r];
        f32x4 b = *reinterpret_cast<const f32x4*>(
            &Li[(32 * kb + kk) * 256 + 32 * bj + c0]);
        acc[0] = fmaf(a, b[0], acc[0]);
        acc[1] = fmaf(a, b[1], acc[1]);
        acc[2] = fmaf(a, b[2], acc[2]);
        acc[3] = fmaf(a, b[3], acc[3]);
      }
    }
    *reinterpret_cast<f32x4*>(&Pinv[(32 * bi + r) * 256 + 32 * bj + c0]) = acc;
    if (bi != bj) {
#pragma unroll
      for (int e = 0; e < 4; ++e)
        Pinv[(32 * bj + c0 + e) * 256 + 32 * bi + r] = acc[e];
    }
    return;
  }
  int b2 = blk - 36;
  int xb = b2 % 3, c = b2 / 3;
  int q = xb * 256 + t;
  float rlam = 2.f / H[(size_t)(256 + c) * DIMH + 256 + c];
  float v;
  if (q < 256) {
    v = Chi[(size_t)q * DIMV + c] * rlam;
  } else {
    int j = q - 256;
    v = (j < c) ? -H[(size_t)(256 + c) * DIMH + 256 + j] * rlam : 0.f;
  }
  Gin[(size_t)c * DIMH + q] = f2bf(v);
}

// ============ K4: Gout = Pinv @ [Y | M] =============================================
__global__ __launch_bounds__(256) void k_gout(const float* __restrict__ Pinv,
                                              const float* __restrict__ H,
                                              const float* __restrict__ Y1,
                                              const float* __restrict__ Chi,
                                              unsigned short* __restrict__ Gout) {
  __shared__ float Ps[32][33], Bs[32][33];
  int q0 = blockIdx.x * 32, i0 = blockIdx.y * 32;
  int t = threadIdx.x;
  int tx = t & 31, ty = t >> 5;
  int lrr = t >> 3, lc4 = (t & 7) * 4;
  float acc[4] = {0.f, 0.f, 0.f, 0.f};
  for (int kc = 0; kc < 8; ++kc) {
    int k0 = kc * 32;
    f32x4 pv = *reinterpret_cast<const f32x4*>(&Pinv[(size_t)(i0 + lrr) * 256 + k0 + lc4]);
    Ps[lrr][lc4 + 0] = pv[0]; Ps[lrr][lc4 + 1] = pv[1];
    Ps[lrr][lc4 + 2] = pv[2]; Ps[lrr][lc4 + 3] = pv[3];
    int k = k0 + lrr;
#pragma unroll
    for (int e = 0; e < 4; ++e) {
      int q = q0 + lc4 + e;
      float v;
      if (q < 256) {
        v = -0.5f * (H[(size_t)k * DIMH + q] + Y1[(size_t)k * 256 + q] - Y1[(size_t)q * 256 + k]);
      } else {
        int c = q - 256;
        v = -(H[(size_t)k * DIMH + 256 + c] + Chi[(size_t)k * DIMV + c]);
      }
      Bs[lrr][lc4 + e] = v;
    }
    __syncthreads();
#pragma unroll
    for (int kk = 0; kk < 32; ++kk) {
      float bb = Bs[kk][tx];
#pragma unroll
      for (int rr = 0; rr < 4; ++rr) acc[rr] = fmaf(Ps[4 * ty + rr][kk], bb, acc[rr]);
    }
    __syncthreads();
  }
#pragma unroll
  for (int rr = 0; rr < 4; ++rr)
    Gout[(size_t)(i0 + 4 * ty + rr) * DIMH + q0 + tx] = f2bf(acc[rr]);
}

// ---------------- K6: fused main v5 (round-11 exact — known 311us) ----------------
#define ACCSTR 33
#define ACC_W 4224
#define DD_W 2048
#define WT_W 2560
#define SMEM_MAIN (4 * (ACC_W + DD_W + WT_W))  // 35328 B

__global__ __launch_bounds__(256, 2) void k_main(const float* __restrict__ x,
                                                 const unsigned short* __restrict__ Gin,
                                                 const unsigned short* __restrict__ Gout,
                                                 const float* __restrict__ bv,
                                                 const float* __restrict__ bx,
                                                 float* __restrict__ out) {
  extern __shared__ char smem[];
  int tid = threadIdx.x;
  int wv = tid >> 6, l = tid & 63;
  int lr = l & 15, lq = l >> 4, koff = lq * 8;
  float* accb = (float*)(smem + wv * ACC_W);
  char* ddiag = smem + 4 * ACC_W + wv * DD_W;
  char* wtmp = smem + 4 * ACC_W + 4 * DD_W + wv * WT_W;

  int rowbase = blockIdx.x * 128 + wv * 32;

  bf16x8 frag0[24], frag1[24];
  {
    u16x8 zz = {0, 0, 0, 0, 0, 0, 0, 0};
#pragma unroll
    for (int c = 8; c < 24; ++c) {
      frag0[c] = __builtin_bit_cast(bf16x8, zz);
      frag1[c] = __builtin_bit_cast(bf16x8, zz);
    }
  }
#pragma unroll
  for (int kc = 0; kc < 8; ++kc) {
    const float* xr0 = x + (size_t)(rowbase + lr) * 256 + koff + kc * 32;
    const float* xr1 = x + (size_t)(rowbase + 16 + lr) * 256 + koff + kc * 32;
    f32x4 a0 = *reinterpret_cast<const f32x4*>(xr0);
    f32x4 a1 = *reinterpret_cast<const f32x4*>(xr0 + 4);
    f32x4 b0 = *reinterpret_cast<const f32x4*>(xr1);
    f32x4 b1 = *reinterpret_cast<const f32x4*>(xr1 + 4);
    u16x8 u0, u1;
#pragma unroll
    for (int e = 0; e < 4; ++e) {
      u0[e] = f2bf(a0[e]); u0[4 + e] = f2bf(a1[e]);
      u1[e] = f2bf(b0[e]); u1[4 + e] = f2bf(b1[e]);
    }
    frag0[kc] = __builtin_bit_cast(bf16x8, u0);
    frag1[kc] = __builtin_bit_cast(bf16x8, u1);
  }

  f32x4 z = {0.f, 0.f, 0.f, 0.f};

#pragma unroll 1
  for (int b = 0; b < 16; ++b) {
#pragma unroll
    for (int t = 0; t < 2; ++t) {
      int row = t * 16 + (l >> 2);
      const unsigned short* src =
          Gin + (size_t)(32 * b + row) * DIMH + 256 + 32 * b + (l & 3) * 8;
      u16x8 v = *reinterpret_cast<const u16x8*>(src);
      *reinterpret_cast<u16x8*>(ddiag + t * 1024 + l * 16) = v;
    }

    f32x4 a00 = z, a01 = z, a10 = z, a11 = z;
    const unsigned short* gb0 = Gin + (size_t)(32 * b + lr) * DIMH + koff;
    const unsigned short* gb1 = gb0 + 16 * DIMH;
#pragma unroll
    for (int g = 0; g < 6; ++g) {
      if (g * 4 < 8 + b) {
#pragma unroll
        for (int cc = 0; cc < 4; ++cc) {
          int c = g * 4 + cc;
          bf16x8 bb0 = ld8(gb0 + c * 32);
          bf16x8 bb1 = ld8(gb1 + c * 32);
          a00 = mfma16(frag0[c], bb0, a00);
          a01 = mfma16(frag0[c], bb1, a01);
          a10 = mfma16(frag1[c], bb0, a10);
          a11 = mfma16(frag1[c], bb1, a11);
        }
      }
    }

    float bv0 = bv[32 * b + lr], bv1 = bv[32 * b + 16 + lr];
#pragma unroll
    for (int r = 0; r < 4; ++r) {
      accb[(lq * 4 + r) * ACCSTR + lr] = a00[r] + bv0;
      accb[(lq * 4 + r) * ACCSTR + 16 + lr] = a01[r] + bv1;
      accb[(16 + lq * 4 + r) * ACCSTR + lr] = a10[r] + bv0;
      accb[(16 + lq * 4 + r) * ACCSTR + 16 + lr] = a11[r] + bv1;
    }

    if (l < 32) {
      const unsigned int* dd = (const unsigned int*)ddiag;
      unsigned int* wrow = (unsigned int*)(wtmp + l * 80);
      float wf[32];
      unsigned int cur = 0;
#pragma unroll
      for (int i = 0; i < 32; ++i) {
        float p0 = 0.f, p1 = 0.f;
        const unsigned int* ddr = dd + i * 16;
#pragma unroll
        for (int j = 0; j < i; ++j) {
          unsigned int pw = ddr[j >> 1];
          float dj = __uint_as_float((j & 1) ? (pw & 0xffff0000u) : (pw << 16));
          if (j & 1) p1 = fmaf(dj, wf[j], p1);
          else       p0 = fmaf(dj, wf[j], p0);
        }
        float s = accb[l * ACCSTR + i] + p0 + p1;
        float e = __builtin_amdgcn_exp2f(s * 2.885390082f);
        float w = fmaf(-2.f, __builtin_amdgcn_rcpf(e + 1.f), 1.f);
        wf[i] = w;
        unsigned int hb = (unsigned int)f2bf(w);
        if (i & 1) { cur |= hb << 16; wrow[i >> 1] = cur; }
        else       cur = hb;
      }
    }

    bf16x8 nw0 = ld8((const unsigned short*)(wtmp + lr * 80 + lq * 16));
    bf16x8 nw1 = ld8((const unsigned short*)(wtmp + (16 + lr) * 80 + lq * 16));
#pragma unroll
    for (int j = 0; j < 16; ++j) {
      if (b == j) { frag0[8 + j] = nw0; frag1[8 + j] = nw1; }
    }
  }

#pragma unroll 1
  for (int ct = 0; ct < 16; ++ct) {
    f32x4 o0 = z, o1 = z;
    const unsigned short* gg = Gout + (size_t)(ct * 16 + lr) * DIMH + koff;
#pragma unroll
    for (int c = 0; c < 24; ++c) {
      bf16x8 bb = ld8(gg + c * 32);
      o0 = mfma16(frag0[c], bb, o0);
      o1 = mfma16(frag1[c], bb, o1);
    }
    float bxv = bx[ct * 16 + lr];
#pragma unroll
    for (int r = 0; r < 4; ++r) {
      out[(size_t)(rowbase + lq * 4 + r) * 256 + ct * 16 + lr] = o0[r] + bxv;
      out[(size_t)(rowbase + 16 + lq * 4 + r) * 256 + ct * 16 + lr] = o1[r] + bxv;
    }
  }
}

extern "C" void kernel_launch(void* const* d_in, const int* in_sizes, int n_in,
                              void* d_out, int out_size, void* d_ws, size_t ws_size,
                              hipStream_t stream) {
  const float* x   = (const float*)d_in[1];
  const float* Pst = (const float*)d_in[2];
  const float* Chi = (const float*)d_in[3];
  const float* X   = (const float*)d_in[4];
  const float* Y1  = (const float*)d_in[5];
  const float* bv  = (const float*)d_in[8];
  const float* bx  = (const float*)d_in[9];
  float* out = (float*)d_out;

  char* ws = (char*)d_ws;
  const size_t OFF_H    = 0;
  const size_t OFF_P    = 2359296;   // P -> L -> Pinv
  const size_t OFF_XHI  = 2883584;
  const size_t OFF_XLO  = 4063232;
  const size_t OFF_GIN  = 5242880;
  const size_t OFF_GOUT = 6029312;   // Li (dead after k_gout) -> Gout
  if (ws_size < 6422528) return;

  float* H    = (float*)(ws + OFF_H);
  float* P    = (float*)(ws + OFF_P);
  float* Li   = (float*)(ws + OFF_GOUT);
  unsigned short* Xhi  = (unsigned short*)(ws + OFF_XHI);
  unsigned short* Xlo  = (unsigned short*)(ws + OFF_XLO);
  unsigned short* Gin  = (unsigned short*)(ws + OFF_GIN);
  unsigned short* Gout = (unsigned short*)(ws + OFF_GOUT);

  k_setup1<<<2560, 256, 0, stream>>>(X, Xhi, Xlo, Pst, P);
  k_setup2<<<145, 1024, 0, stream>>>(P, Li, Xhi, Xlo, H);
  k_setup3<<<1572, 256, 0, stream>>>(H, Chi, Gin, Li, P);
  dim3 go(24, 8);
  k_gout<<<go, 256, 0, stream>>>(P, H, Y1, Chi, Gout);
  k_main<<<512, 256, SMEM_MAIN, stream>>>(x, Gin, Gout, bv, bx, out);
}

// Round 18
// 606.496 us; speedup vs baseline: 1.4840x; 1.4840x over previous
//
#include <hip/hip_runtime.h>
#include <cstdint>
#include <cstddef>

#define DIMX 256
#define DIMV 512
#define DIMH 768
#define EPSV 0.05f

typedef __bf16 bf16x8 __attribute__((ext_vector_type(8)));
typedef unsigned short u16x8 __attribute__((ext_vector_type(8)));
typedef unsigned int u32x4 __attribute__((ext_vector_type(4)));
typedef float f32x4 __attribute__((ext_vector_type(4)));

__device__ __forceinline__ unsigned short f2bf(float f) {
  unsigned int u = __float_as_uint(f);
  u += 0x7fffu + ((u >> 16) & 1u);
  return (unsigned short)(u >> 16);
}
__device__ __forceinline__ float bf2f(unsigned short b) {
  return __uint_as_float(((unsigned int)b) << 16);
}
__device__ __forceinline__ bf16x8 ld8(const unsigned short* p) {
  u16x8 u = *reinterpret_cast<const u16x8*>(p);
  return __builtin_bit_cast(bf16x8, u);
}
__device__ __forceinline__ f32x4 mfma16(bf16x8 a, bf16x8 b, f32x4 c) {
  return __builtin_amdgcn_mfma_f32_16x16x32_bf16(a, b, c, 0, 0, 0);
}
__device__ __forceinline__ float rdlane(float v, int lane) {
  return __uint_as_float(
      (unsigned int)__builtin_amdgcn_readlane((int)__float_as_uint(v), lane));
}

// ============ K1: syrkP (blocks 0..255)  UNION  split (blocks 256..2559) ============
__global__ __launch_bounds__(256) void k_setup1(const float* __restrict__ X,
                                                unsigned short* __restrict__ Xhi,
                                                unsigned short* __restrict__ Xlo,
                                                const float* __restrict__ Pst,
                                                float* __restrict__ P) {
  int blk = blockIdx.x;
  if (blk < 256) {
    int bi = blk >> 4, bj = blk & 15;
    int ty = threadIdx.x >> 4, tx = threadIdx.x & 15;
    int i = bi * 16 + ty, j = bj * 16 + tx;
    const f32x4* ra = reinterpret_cast<const f32x4*>(Pst + (size_t)i * DIMX);
    const f32x4* rb = reinterpret_cast<const f32x4*>(Pst + (size_t)j * DIMX);
    float s = 0.f;
    for (int k = 0; k < 64; ++k) {
      f32x4 a = ra[k], b = rb[k];
      s = fmaf(a[0], b[0], s); s = fmaf(a[1], b[1], s);
      s = fmaf(a[2], b[2], s); s = fmaf(a[3], b[3], s);
    }
    P[(size_t)i * DIMX + j] = 0.5f * s + (i == j ? EPSV : 0.f);
  } else {
    int idx = (blk - 256) * 256 + threadIdx.x;
    if (idx < DIMH * DIMH) {
      float f = X[idx];
      unsigned short h = f2bf(f);
      Xhi[idx] = h;
      Xlo[idx] = f2bf(f - bf2f(h));
    }
  }
}

// ============ K2: chol + Linv (block 0, 256 thr)  UNION  syrkH (blocks 1..144) ======
// Round-16 proven version (total 606us). Round-17 lesson: 1024-thread blocks are
// hard-capped at 64 arch-VGPRs by hipcc (4th confirmation) -> serial d[32]/wcol[32]
// state spills -> 3x regression. Stay at 256 threads.
__global__ __launch_bounds__(256, 1) void k_setup2(float* __restrict__ A,
                                                   float* __restrict__ Li,
                                                   const unsigned short* __restrict__ Xhi,
                                                   const unsigned short* __restrict__ Xlo,
                                                   float* __restrict__ H) {
  __shared__ float Wl[32][33];
  __shared__ float T[32][232];    // TRSM staging; later Linv T-scratch (7424 f32)
  __shared__ float Lp2[224][33];  // Linv: L row-panel staged transposed
  if (blockIdx.x == 0) {
    int t = threadIdx.x;
    int wv = t >> 6, l = t & 63;
#pragma unroll 1
    for (int s = 0; s < 8; ++s) {
      int K = 32 * s;
      int R32 = 256 - K - 32;
      if (wv == 0) {
        int li = l & 31;
        float d[32];
#pragma unroll
        for (int j = 0; j < 32; ++j) d[j] = A[(K + j) * 256 + K + li];
#pragma unroll
        for (int k = 0; k < 32; ++k) {
          float dkk = rdlane(d[k], k);
          float ip = rsqrtf(dkk);
          d[k] *= ip;
#pragma unroll
          for (int j = k + 1; j < 32; ++j) {
            float ljk = rdlane(d[k], j);
            d[j] = fmaf(-ljk, d[k], d[j]);
          }
        }
        float wcol[32];
#pragma unroll
        for (int i = 0; i < 32; ++i) {
          float Lii = rdlane(d[i], i);
          float ipi = 1.0f / Lii;
          float acc = (li == i) ? 1.0f : 0.0f;
#pragma unroll
          for (int k = 0; k < i; ++k) {
            float Lik = rdlane(d[k], i);
            acc = fmaf(-Lik, wcol[k], acc);
          }
          wcol[i] = acc * ipi;
        }
        if (l < 32) {
#pragma unroll
          for (int k = 0; k < 32; ++k) {
            Wl[k][l] = wcol[k];
            Li[(32 * s + k) * 256 + 32 * s + l] = wcol[k];  // Linv diag = W_s
          }
        }
      }
      __syncthreads();
      if (R32 > 0) {
        int nrt = R32 >> 2;
        for (int u = t; u < nrt * 8; u += 256) {
          int rt = u >> 3, jg = u & 7;
          int r = K + 32 + rt * 4;
          int j0 = jg * 4;
          f32x4 z4 = {0.f, 0.f, 0.f, 0.f};
          f32x4 acc[4] = {z4, z4, z4, z4};
#pragma unroll
          for (int k = 0; k < 32; ++k) {
            f32x4 av = *reinterpret_cast<const f32x4*>(&A[(K + k) * 256 + r]);
#pragma unroll
            for (int jj = 0; jj < 4; ++jj) {
              float w = Wl[j0 + jj][k];
              acc[jj][0] = fmaf(av[0], w, acc[jj][0]);
              acc[jj][1] = fmaf(av[1], w, acc[jj][1]);
              acc[jj][2] = fmaf(av[2], w, acc[jj][2]);
              acc[jj][3] = fmaf(av[3], w, acc[jj][3]);
            }
          }
#pragma unroll
          for (int jj = 0; jj < 4; ++jj)
            *reinterpret_cast<f32x4*>(&T[j0 + jj][rt * 4]) = acc[jj];
        }
        __syncthreads();
#pragma unroll 1
        for (int j = 0; j < 32; ++j) {
          int rl = t << 2;
          if (rl < R32)
            *reinterpret_cast<f32x4*>(&A[(K + j) * 256 + K + 32 + rl]) =
                *reinterpret_cast<const f32x4*>(&T[j][rl]);
        }
        int T4 = R32 >> 2;
        int ntile = T4 * (T4 + 1) / 2;
        for (int idx = t; idx < ntile; idx += 256) {
          int ti = (int)((sqrtf(8.0f * (float)idx + 1.0f) - 1.0f) * 0.5f);
          while ((ti + 1) * (ti + 2) / 2 <= idx) ++ti;
          while (ti * (ti + 1) / 2 > idx) --ti;
          int tj = idx - ti * (ti + 1) / 2;
          int gi = K + 32 + 4 * ti, gj = K + 32 + 4 * tj;
          f32x4 acc[4];
#pragma unroll
          for (int jj = 0; jj < 4; ++jj)
            acc[jj] = *reinterpret_cast<const f32x4*>(&A[(gj + jj) * 256 + gi]);
#pragma unroll
          for (int k = 0; k < 32; ++k) {
            f32x4 av = *reinterpret_cast<const f32x4*>(&T[k][4 * ti]);
            f32x4 bv = *reinterpret_cast<const f32x4*>(&T[k][4 * tj]);
#pragma unroll
            for (int jj = 0; jj < 4; ++jj) {
              acc[jj][0] = fmaf(-av[0], bv[jj], acc[jj][0]);
              acc[jj][1] = fmaf(-av[1], bv[jj], acc[jj][1]);
              acc[jj][2] = fmaf(-av[2], bv[jj], acc[jj][2]);
              acc[jj][3] = fmaf(-av[3], bv[jj], acc[jj][3]);
            }
          }
#pragma unroll
          for (int jj = 0; jj < 4; ++jj)
            *reinterpret_cast<f32x4*>(&A[(gj + jj) * 256 + gi]) = acc[jj];
        }
      }
      __syncthreads();
    }

    // ---- Linv levels: for i=1..7, Linv_ij = -W_i * (sum_{k=j}^{i-1} L_ik Linv_kj) ----
    float* Tb = &T[0][0];
#pragma unroll 1
    for (int i = 1; i < 8; ++i) {
      for (int idx = t; idx < 32 * 32 * i; idx += 256) {
        int r = idx & 31, cc = idx >> 5;
        Lp2[cc][r] = A[cc * 256 + 32 * i + r];
      }
      for (int idx = t; idx < 1024; idx += 256) {
        int r = idx >> 5, kk = idx & 31;
        Wl[r][kk] = Li[(32 * i + r) * 256 + 32 * i + kk];
      }
      __syncthreads();
      int nt1 = i * 64;
      for (int u = t; u < nt1; u += 256) {
        int j = u >> 6, v = u & 63;
        int r0 = (v >> 3) * 4, c0 = (v & 7) * 4;
        f32x4 z4 = {0.f, 0.f, 0.f, 0.f};
        f32x4 acc[4] = {z4, z4, z4, z4};
        for (int k = j; k < i; ++k) {
#pragma unroll
          for (int kk = 0; kk < 32; ++kk) {
            f32x4 lv = *reinterpret_cast<const f32x4*>(
                &Li[(32 * k + kk) * 256 + 32 * j + c0]);
#pragma unroll
            for (int e = 0; e < 4; ++e) {
              float lpe = Lp2[32 * k + kk][r0 + e];
              acc[e][0] = fmaf(lpe, lv[0], acc[e][0]);
              acc[e][1] = fmaf(lpe, lv[1], acc[e][1]);
              acc[e][2] = fmaf(lpe, lv[2], acc[e][2]);
              acc[e][3] = fmaf(lpe, lv[3], acc[e][3]);
            }
          }
        }
#pragma unroll
        for (int e = 0; e < 4; ++e)
          *reinterpret_cast<f32x4*>(&Tb[j * 1024 + (r0 + e) * 32 + c0]) = acc[e];
      }
      __syncthreads();
      for (int u = t; u < nt1; u += 256) {
        int j = u >> 6, v = u & 63;
        int r0 = (v >> 3) * 4, c0 = (v & 7) * 4;
        f32x4 z4 = {0.f, 0.f, 0.f, 0.f};
        f32x4 acc[4] = {z4, z4, z4, z4};
#pragma unroll
        for (int kk = 0; kk < 32; ++kk) {
          f32x4 tv = *reinterpret_cast<const f32x4*>(&Tb[j * 1024 + kk * 32 + c0]);
#pragma unroll
          for (int e = 0; e < 4; ++e) {
            float w = Wl[r0 + e][kk];
            acc[e][0] = fmaf(-w, tv[0], acc[e][0]);
            acc[e][1] = fmaf(-w, tv[1], acc[e][1]);
            acc[e][2] = fmaf(-w, tv[2], acc[e][2]);
            acc[e][3] = fmaf(-w, tv[3], acc[e][3]);
          }
        }
#pragma unroll
        for (int e = 0; e < 4; ++e)
          *reinterpret_cast<f32x4*>(&Li[(32 * i + r0 + e) * 256 + 32 * j + c0]) =
              acc[e];
      }
      __syncthreads();
    }
  } else {
    // ---- syrkH: H = X@X^T + eps*I via bf16x2 split MFMA ----
    int b2 = blockIdx.x - 1;
    int bx = b2 % 12, by = b2 / 12;
    int i0 = by * 64, j0 = bx * 64;
    int l = threadIdx.x & 63, wv = threadIdx.x >> 6;
    int lr = l & 15, lq = l >> 4;
    int koff = lq * 8;
    int arow = i0 + wv * 16 + lr;
    f32x4 z = {0.f, 0.f, 0.f, 0.f};
    f32x4 acc[4] = {z, z, z, z};
    for (int pass = 0; pass < 3; ++pass) {
      const unsigned short* Xa = (pass == 2) ? Xlo : Xhi;
      const unsigned short* Xb = (pass == 1) ? Xlo : Xhi;
      for (int kc = 0; kc < 24; ++kc) {
        bf16x8 a = ld8(&Xa[(size_t)arow * DIMH + kc * 32 + koff]);
#pragma unroll
        for (int ct = 0; ct < 4; ++ct) {
          bf16x8 b = ld8(&Xb[(size_t)(j0 + ct * 16 + lr) * DIMH + kc * 32 + koff]);
          acc[ct] = mfma16(a, b, acc[ct]);
        }
      }
    }
#pragma unroll
    for (int ct = 0; ct < 4; ++ct)
#pragma unroll
      for (int r = 0; r < 4; ++r) {
        int i = i0 + wv * 16 + lq * 4 + r;
        int j = j0 + ct * 16 + lr;
        H[(size_t)i * DIMH + j] = acc[ct][r] + (i == j ? EPSV : 0.f);
      }
  }
}

// ============ K3: pinv (blocks 0..35)  UNION  gin (blocks 36..1571) =================
__global__ __launch_bounds__(256, 2) void k_setup3(const float* __restrict__ H,
                                                   const float* __restrict__ Chi,
                                                   unsigned short* __restrict__ Gin,
                                                   const float* __restrict__ Li,
                                                   float* __restrict__ Pinv) {
  int blk = blockIdx.x;
  int t = threadIdx.x;
  if (blk < 36) {
    int bi = (int)((sqrtf(8.0f * (float)blk + 1.0f) - 1.0f) * 0.5f);
    while ((bi + 1) * (bi + 2) / 2 <= blk) ++bi;
    while (bi * (bi + 1) / 2 > blk) --bi;
    int bj = blk - bi * (bi + 1) / 2;
    int r = t >> 3, c0 = (t & 7) * 4;
    f32x4 acc = {0.f, 0.f, 0.f, 0.f};
    for (int kb = bi; kb < 8; ++kb) {
#pragma unroll
      for (int kk = 0; kk < 32; ++kk) {
        float a = Li[(32 * kb + kk) * 256 + 32 * bi + r];
        f32x4 b = *reinterpret_cast<const f32x4*>(
            &Li[(32 * kb + kk) * 256 + 32 * bj + c0]);
        acc[0] = fmaf(a, b[0], acc[0]);
        acc[1] = fmaf(a, b[1], acc[1]);
        acc[2] = fmaf(a, b[2], acc[2]);
        acc[3] = fmaf(a, b[3], acc[3]);
      }
    }
    *reinterpret_cast<f32x4*>(&Pinv[(32 * bi + r) * 256 + 32 * bj + c0]) = acc;
    if (bi != bj) {
#pragma unroll
      for (int e = 0; e < 4; ++e)
        Pinv[(32 * bj + c0 + e) * 256 + 32 * bi + r] = acc[e];
    }
    return;
  }
  int b2 = blk - 36;
  int xb = b2 % 3, c = b2 / 3;
  int q = xb * 256 + t;
  float rlam = 2.f / H[(size_t)(256 + c) * DIMH + 256 + c];
  float v;
  if (q < 256) {
    v = Chi[(size_t)q * DIMV + c] * rlam;
  } else {
    int j = q - 256;
    v = (j < c) ? -H[(size_t)(256 + c) * DIMH + 256 + j] * rlam : 0.f;
  }
  Gin[(size_t)c * DIMH + q] = f2bf(v);
}

// ============ K4: Gout = Pinv @ [Y | M] =============================================
__global__ __launch_bounds__(256) void k_gout(const float* __restrict__ Pinv,
                                              const float* __restrict__ H,
                                              const float* __restrict__ Y1,
                                              const float* __restrict__ Chi,
                                              unsigned short* __restrict__ Gout) {
  __shared__ float Ps[32][33], Bs[32][33];
  int q0 = blockIdx.x * 32, i0 = blockIdx.y * 32;
  int t = threadIdx.x;
  int tx = t & 31, ty = t >> 5;
  int lrr = t >> 3, lc4 = (t & 7) * 4;
  float acc[4] = {0.f, 0.f, 0.f, 0.f};
  for (int kc = 0; kc < 8; ++kc) {
    int k0 = kc * 32;
    f32x4 pv = *reinterpret_cast<const f32x4*>(&Pinv[(size_t)(i0 + lrr) * 256 + k0 + lc4]);
    Ps[lrr][lc4 + 0] = pv[0]; Ps[lrr][lc4 + 1] = pv[1];
    Ps[lrr][lc4 + 2] = pv[2]; Ps[lrr][lc4 + 3] = pv[3];
    int k = k0 + lrr;
#pragma unroll
    for (int e = 0; e < 4; ++e) {
      int q = q0 + lc4 + e;
      float v;
      if (q < 256) {
        v = -0.5f * (H[(size_t)k * DIMH + q] + Y1[(size_t)k * 256 + q] - Y1[(size_t)q * 256 + k]);
      } else {
        int c = q - 256;
        v = -(H[(size_t)k * DIMH + 256 + c] + Chi[(size_t)k * DIMV + c]);
      }
      Bs[lrr][lc4 + e] = v;
    }
    __syncthreads();
#pragma unroll
    for (int kk = 0; kk < 32; ++kk) {
      float bb = Bs[kk][tx];
#pragma unroll
      for (int rr = 0; rr < 4; ++rr) acc[rr] = fmaf(Ps[4 * ty + rr][kk], bb, acc[rr]);
    }
    __syncthreads();
  }
#pragma unroll
  for (int rr = 0; rr < 4; ++rr)
    Gout[(size_t)(i0 + 4 * ty + rr) * DIMH + q0 + tx] = f2bf(acc[rr]);
}

// ---------------- K6: fused main v5 (round-11 exact — known 311us) ----------------
#define ACCSTR 33
#define ACC_W 4224
#define DD_W 2048
#define WT_W 2560
#define SMEM_MAIN (4 * (ACC_W + DD_W + WT_W))  // 35328 B

__global__ __launch_bounds__(256, 2) void k_main(const float* __restrict__ x,
                                                 const unsigned short* __restrict__ Gin,
                                                 const unsigned short* __restrict__ Gout,
                                                 const float* __restrict__ bv,
                                                 const float* __restrict__ bx,
                                                 float* __restrict__ out) {
  extern __shared__ char smem[];
  int tid = threadIdx.x;
  int wv = tid >> 6, l = tid & 63;
  int lr = l & 15, lq = l >> 4, koff = lq * 8;
  float* accb = (float*)(smem + wv * ACC_W);
  char* ddiag = smem + 4 * ACC_W + wv * DD_W;
  char* wtmp = smem + 4 * ACC_W + 4 * DD_W + wv * WT_W;

  int rowbase = blockIdx.x * 128 + wv * 32;

  bf16x8 frag0[24], frag1[24];
  {
    u16x8 zz = {0, 0, 0, 0, 0, 0, 0, 0};
#pragma unroll
    for (int c = 8; c < 24; ++c) {
      frag0[c] = __builtin_bit_cast(bf16x8, zz);
      frag1[c] = __builtin_bit_cast(bf16x8, zz);
    }
  }
#pragma unroll
  for (int kc = 0; kc < 8; ++kc) {
    const float* xr0 = x + (size_t)(rowbase + lr) * 256 + koff + kc * 32;
    const float* xr1 = x + (size_t)(rowbase + 16 + lr) * 256 + koff + kc * 32;
    f32x4 a0 = *reinterpret_cast<const f32x4*>(xr0);
    f32x4 a1 = *reinterpret_cast<const f32x4*>(xr0 + 4);
    f32x4 b0 = *reinterpret_cast<const f32x4*>(xr1);
    f32x4 b1 = *reinterpret_cast<const f32x4*>(xr1 + 4);
    u16x8 u0, u1;
#pragma unroll
    for (int e = 0; e < 4; ++e) {
      u0[e] = f2bf(a0[e]); u0[4 + e] = f2bf(a1[e]);
      u1[e] = f2bf(b0[e]); u1[4 + e] = f2bf(b1[e]);
    }
    frag0[kc] = __builtin_bit_cast(bf16x8, u0);
    frag1[kc] = __builtin_bit_cast(bf16x8, u1);
  }

  f32x4 z = {0.f, 0.f, 0.f, 0.f};

#pragma unroll 1
  for (int b = 0; b < 16; ++b) {
#pragma unroll
    for (int t = 0; t < 2; ++t) {
      int row = t * 16 + (l >> 2);
      const unsigned short* src =
          Gin + (size_t)(32 * b + row) * DIMH + 256 + 32 * b + (l & 3) * 8;
      u16x8 v = *reinterpret_cast<const u16x8*>(src);
      *reinterpret_cast<u16x8*>(ddiag + t * 1024 + l * 16) = v;
    }

    f32x4 a00 = z, a01 = z, a10 = z, a11 = z;
    const unsigned short* gb0 = Gin + (size_t)(32 * b + lr) * DIMH + koff;
    const unsigned short* gb1 = gb0 + 16 * DIMH;
#pragma unroll
    for (int g = 0; g < 6; ++g) {
      if (g * 4 < 8 + b) {
#pragma unroll
        for (int cc = 0; cc < 4; ++cc) {
          int c = g * 4 + cc;
          bf16x8 bb0 = ld8(gb0 + c * 32);
          bf16x8 bb1 = ld8(gb1 + c * 32);
          a00 = mfma16(frag0[c], bb0, a00);
          a01 = mfma16(frag0[c], bb1, a01);
          a10 = mfma16(frag1[c], bb0, a10);
          a11 = mfma16(frag1[c], bb1, a11);
        }
      }
    }

    float bv0 = bv[32 * b + lr], bv1 = bv[32 * b + 16 + lr];
#pragma unroll
    for (int r = 0; r < 4; ++r) {
      accb[(lq * 4 + r) * ACCSTR + lr] = a00[r] + bv0;
      accb[(lq * 4 + r) * ACCSTR + 16 + lr] = a01[r] + bv1;
      accb[(16 + lq * 4 + r) * ACCSTR + lr] = a10[r] + bv0;
      accb[(16 + lq * 4 + r) * ACCSTR + 16 + lr] = a11[r] + bv1;
    }

    if (l < 32) {
      const unsigned int* dd = (const unsigned int*)ddiag;
      unsigned int* wrow = (unsigned int*)(wtmp + l * 80);
      float wf[32];
      unsigned int cur = 0;
#pragma unroll
      for (int i = 0; i < 32; ++i) {
        float p0 = 0.f, p1 = 0.f;
        const unsigned int* ddr = dd + i * 16;
#pragma unroll
        for (int j = 0; j < i; ++j) {
          unsigned int pw = ddr[j >> 1];
          float dj = __uint_as_float((j & 1) ? (pw & 0xffff0000u) : (pw << 16));
          if (j & 1) p1 = fmaf(dj, wf[j], p1);
          else       p0 = fmaf(dj, wf[j], p0);
        }
        float s = accb[l * ACCSTR + i] + p0 + p1;
        float e = __builtin_amdgcn_exp2f(s * 2.885390082f);
        float w = fmaf(-2.f, __builtin_amdgcn_rcpf(e + 1.f), 1.f);
        wf[i] = w;
        unsigned int hb = (unsigned int)f2bf(w);
        if (i & 1) { cur |= hb << 16; wrow[i >> 1] = cur; }
        else       cur = hb;
      }
    }

    bf16x8 nw0 = ld8((const unsigned short*)(wtmp + lr * 80 + lq * 16));
    bf16x8 nw1 = ld8((const unsigned short*)(wtmp + (16 + lr) * 80 + lq * 16));
#pragma unroll
    for (int j = 0; j < 16; ++j) {
      if (b == j) { frag0[8 + j] = nw0; frag1[8 + j] = nw1; }
    }
  }

#pragma unroll 1
  for (int ct = 0; ct < 16; ++ct) {
    f32x4 o0 = z, o1 = z;
    const unsigned short* gg = Gout + (size_t)(ct * 16 + lr) * DIMH + koff;
#pragma unroll
    for (int c = 0; c < 24; ++c) {
      bf16x8 bb = ld8(gg + c * 32);
      o0 = mfma16(frag0[c], bb, o0);
      o1 = mfma16(frag1[c], bb, o1);
    }
    float bxv = bx[ct * 16 + lr];
#pragma unroll
    for (int r = 0; r < 4; ++r) {
      out[(size_t)(rowbase + lq * 4 + r) * 256 + ct * 16 + lr] = o0[r] + bxv;
      out[(size_t)(rowbase + 16 + lq * 4 + r) * 256 + ct * 16 + lr] = o1[r] + bxv;
    }
  }
}

extern "C" void kernel_launch(void* const* d_in, const int* in_sizes, int n_in,
                              void* d_out, int out_size, void* d_ws, size_t ws_size,
                              hipStream_t stream) {
  const float* x   = (const float*)d_in[1];
  const float* Pst = (const float*)d_in[2];
  const float* Chi = (const float*)d_in[3];
  const float* X   = (const float*)d_in[4];
  const float* Y1  = (const float*)d_in[5];
  const float* bv  = (const float*)d_in[8];
  const float* bx  = (const float*)d_in[9];
  float* out = (float*)d_out;

  char* ws = (char*)d_ws;
  const size_t OFF_H    = 0;
  const size_t OFF_P    = 2359296;   // P -> L -> Pinv (256KB)
  const size_t OFF_XHI  = 2883584;
  const size_t OFF_XLO  = 4063232;
  const size_t OFF_GIN  = 5242880;
  const size_t OFF_GOUT = 6029312;   // Li (256KB, dead after setup3) -> Gout
  if (ws_size < 6422528) return;

  float* H    = (float*)(ws + OFF_H);
  float* P    = (float*)(ws + OFF_P);
  float* Li   = (float*)(ws + OFF_GOUT);
  unsigned short* Xhi  = (unsigned short*)(ws + OFF_XHI);
  unsigned short* Xlo  = (unsigned short*)(ws + OFF_XLO);
  unsigned short* Gin  = (unsigned short*)(ws + OFF_GIN);
  unsigned short* Gout = (unsigned short*)(ws + OFF_GOUT);

  k_setup1<<<2560, 256, 0, stream>>>(X, Xhi, Xlo, Pst, P);
  k_setup2<<<145, 256, 0, stream>>>(P, Li, Xhi, Xlo, H);
  k_setup3<<<1572, 256, 0, stream>>>(H, Chi, Gin, Li, P);
  dim3 go(24, 8);
  k_gout<<<go, 256, 0, stream>>>(P, H, Y1, Chi, Gout);
  k_main<<<512, 256, SMEM_MAIN, stream>>>(x, Gin, Gout, bv, bx, out);
}